// Round 19
// baseline (361.414 us; speedup 1.0000x reference)
//
#include <hip/hip_runtime.h>
#include <hip/hip_bf16.h>
#include <stdint.h>

typedef __attribute__((ext_vector_type(8))) __bf16 bf16x8;
typedef __attribute__((ext_vector_type(4))) __bf16 bf16x4;
typedef __attribute__((ext_vector_type(4))) float  f32x4;

#define NTOK   8192
#define DMODEL 1024
#define HDIM   4096
#define NEXP   8
#define PSTRIDE 10240   // partial-buffer row capacity (sorted rows, 256-pad max)

__device__ __forceinline__ void glds16(const void* g, void* l) {
  __builtin_amdgcn_global_load_lds(
      (const __attribute__((address_space(1))) uint32_t*)g,
      (__attribute__((address_space(3))) uint32_t*)l, 16, 0, 0);
}

#define WAITV(N) asm volatile("s_waitcnt vmcnt(" #N ")" ::: "memory")
#define SBAR()  do { __builtin_amdgcn_sched_barrier(0); \
                     __builtin_amdgcn_s_barrier();      \
                     __builtin_amdgcn_sched_barrier(0); } while (0)

// ------------------------------------------------------------------ utils
__global__ void zero_cnt_kernel(int* cnt) {
  if (threadIdx.x < NEXP) cnt[threadIdx.x] = 0;
}

// base[e+1] = base[e] + round256(cnt[e])   (256-row M-tiles)
__global__ void prefix_kernel(const int* __restrict__ cnt, int* __restrict__ base) {
  if (threadIdx.x == 0) {
    int b = 0;
    base[0] = 0;
    for (int e = 0; e < NEXP; ++e) {
      b += (cnt[e] + 255) & ~255;
      base[e + 1] = b;
    }
  }
}

// ------------------------------------------------------------------ bodies
__device__ void gate_body(int bid,
    const float* __restrict__ x, const float* __restrict__ gw,
    const float* __restrict__ gb, float* __restrict__ wgt,
    int* __restrict__ cnt, int* __restrict__ meta)
{
  const int lane = threadIdx.x & 63;
  const int wv   = threadIdx.x >> 6;
  const int t    = (bid << 2) + wv;
  const float* xp = x + (size_t)t * DMODEL;

  float acc[NEXP];
#pragma unroll
  for (int e = 0; e < NEXP; ++e) acc[e] = 0.f;

#pragma unroll
  for (int j = 0; j < 4; ++j) {
    const int d = j * 256 + lane * 4;
    const float4 xv = *(const float4*)(xp + d);
    const float xs[4] = {xv.x, xv.y, xv.z, xv.w};
#pragma unroll
    for (int dd = 0; dd < 4; ++dd) {
      const float4 g0 = *(const float4*)(gw + (size_t)(d + dd) * NEXP);
      const float4 g1 = *(const float4*)(gw + (size_t)(d + dd) * NEXP + 4);
      acc[0] = fmaf(xs[dd], g0.x, acc[0]);
      acc[1] = fmaf(xs[dd], g0.y, acc[1]);
      acc[2] = fmaf(xs[dd], g0.z, acc[2]);
      acc[3] = fmaf(xs[dd], g0.w, acc[3]);
      acc[4] = fmaf(xs[dd], g1.x, acc[4]);
      acc[5] = fmaf(xs[dd], g1.y, acc[5]);
      acc[6] = fmaf(xs[dd], g1.z, acc[6]);
      acc[7] = fmaf(xs[dd], g1.w, acc[7]);
    }
  }
#pragma unroll
  for (int e = 0; e < NEXP; ++e) {
#pragma unroll
    for (int off = 32; off > 0; off >>= 1)
      acc[e] += __shfl_xor(acc[e], off, 64);
  }
  if (lane == 0) {
    float l[NEXP];
#pragma unroll
    for (int e = 0; e < NEXP; ++e) l[e] = acc[e] + gb[e];
    int i1 = 0; float m1 = l[0];
#pragma unroll
    for (int e = 1; e < NEXP; ++e) if (l[e] > m1) { m1 = l[e]; i1 = e; }
    int i2 = -1; float m2 = -3.402823466e38f;
#pragma unroll
    for (int e = 0; e < NEXP; ++e) if (e != i1 && l[e] > m2) { m2 = l[e]; i2 = e; }
    const int es = i1 > i2 ? i1 : i2;   // reference: last expert in loop wins
    float s = 0.f;
#pragma unroll
    for (int e = 0; e < NEXP; ++e) s += expf(l[e] - m1);
    const float w = expf(l[es] - m1) / s;
    wgt[t] = w;
    const int pos = atomicAdd(&cnt[es], 1);
    meta[t] = (es << 13) | pos;
  }
}

// pack_w via LDS transpose, 128k x 128n tile (r18 body):
// src [E][K][N] fp32 -> dst [E][N][K] bf16 (k-contig rows; GEMM layout).
template<int N, int K>
__device__ void packw_body(int bid, const float* __restrict__ src,
                           __bf16* __restrict__ dst)
{
  const int NP = N / 128;
  const int np = bid % NP;
  const int e  = (bid / NP) % NEXP;
  const int kt = bid / (NP * NEXP);     // < K/128
  const int t = threadIdx.x;
  __shared__ __bf16 sh[16384];          // 128 k x 128 n (granule-4 rotated)

  const float* sp = src + (size_t)e * K * N + (size_t)(kt * 128) * N + np * 128;
  const int g  = t & 31;                // col granule (4 floats)
  const int kb = t >> 5;                // 0..7

  float4 vv[16];
#pragma unroll
  for (int i = 0; i < 16; ++i)
    vv[i] = *(const float4*)(sp + (size_t)(kb + 8 * i) * N + g * 4);

#pragma unroll
  for (int i = 0; i < 16; ++i) {
    const int k = kb + 8 * i;
    bf16x4 o;
    o[0] = (__bf16)vv[i].x; o[1] = (__bf16)vv[i].y;
    o[2] = (__bf16)vv[i].z; o[3] = (__bf16)vv[i].w;
    const int pg = (g + 2 * (k >> 3) + (k & 1)) & 31;
    *(bf16x4*)&sh[k * 128 + pg * 4] = o;
  }
  __syncthreads();

  __bf16* dbase = dst + ((size_t)e * N + np * 128) * K + kt * 128;
  const int ks8 = t & 15;
  const int nb  = t >> 4;               // 0..15
#pragma unroll
  for (int i = 0; i < 8; ++i) {
    const int n = nb + 16 * i;
    bf16x8 v;
#pragma unroll
    for (int j = 0; j < 8; ++j) {
      const int k = ks8 * 8 + j;
      const int pg = ((n >> 2) + 2 * (k >> 3) + (k & 1)) & 31;
      v[j] = sh[k * 128 + pg * 4 + (n & 3)];
    }
    *(bf16x8*)(dbase + (size_t)n * K + ks8 * 8) = v;
  }
}

// fused A, INTERLEAVED streams: bid%3 -> {gate, pack_w1, pack_w2}
__global__ __launch_bounds__(256) void fusedA_kernel(
    const float* __restrict__ x, const float* __restrict__ gw,
    const float* __restrict__ gb, float* __restrict__ wgt,
    int* __restrict__ cnt, int* __restrict__ meta,
    const float* __restrict__ w1, __bf16* __restrict__ w1p,
    const float* __restrict__ w2, __bf16* __restrict__ w2p)
{
  const int c = blockIdx.x / 3, sel = blockIdx.x % 3;
  if (sel == 0)      gate_body(c, x, gw, gb, wgt, cnt, meta);
  else if (sel == 1) packw_body<HDIM, DMODEL>(c, w1, w1p);   // 2048
  else               packw_body<DMODEL, HDIM>(c, w2, w2p);   // 2048
}

// fused A fallback (gate + w1 only): bid%2, 4096 blocks
__global__ __launch_bounds__(256) void fusedA2_kernel(
    const float* __restrict__ x, const float* __restrict__ gw,
    const float* __restrict__ gb, float* __restrict__ wgt,
    int* __restrict__ cnt, int* __restrict__ meta,
    const float* __restrict__ w1, __bf16* __restrict__ w1p)
{
  const int c = blockIdx.x / 2, sel = blockIdx.x % 2;
  if (sel == 0) gate_body(c, x, gw, gb, wgt, cnt, meta);
  else          packw_body<HDIM, DMODEL>(c, w1, w1p);
}

// standalone pack_w (serial fallback for w2): 2048 blocks
template<int N, int K>
__global__ __launch_bounds__(256) void pack_w_kernel(
    const float* __restrict__ src, __bf16* __restrict__ dst)
{
  packw_body<N, K>(blockIdx.x, src, dst);
}

// -------------------------------------------------- pack x (sorted order)
__global__ __launch_bounds__(256) void pack_x_kernel(
    const float* __restrict__ x, const float* __restrict__ wgt,
    const int* __restrict__ meta, const int* __restrict__ base,
    __bf16* __restrict__ xbf, int* __restrict__ sortmap)
{
  const int t = blockIdx.x * 2 + (threadIdx.x >> 7);
  const int l = threadIdx.x & 127;
  const int m = meta[t];
  const int es = m >> 13, pos = m & 8191;
  const int dst = base[es] + pos;
  const float w = wgt[t];
  const float4 a = *(const float4*)(x + (size_t)t * DMODEL + l * 8);
  const float4 b = *(const float4*)(x + (size_t)t * DMODEL + l * 8 + 4);
  bf16x8 o;
  o[0] = (__bf16)(a.x * w); o[1] = (__bf16)(a.y * w);
  o[2] = (__bf16)(a.z * w); o[3] = (__bf16)(a.w * w);
  o[4] = (__bf16)(b.x * w); o[5] = (__bf16)(b.y * w);
  o[6] = (__bf16)(b.z * w); o[7] = (__bf16)(b.w * w);
  *(bf16x8*)(xbf + (size_t)dst * DMODEL + l * 8) = o;
  if (l == 0) sortmap[dst] = t;
}

// ------------------------------------------------------------------ GEMM
// r7's verified core + r10-verified split-K decode. 256x256 tile, 8 waves,
// BK=64, 2-buffer LDS (128KB), per K-tile { WAITV(0); barrier; stage next;
// compute }. Swizzle at glds SOURCE (wave-uniform linear dest, m104 rule).
// SPLITK>1: y = kh*40 + m; each kh computes K/SPLITK and writes a bf16
// partial (sorted rows) to outp[kh*PSTRIDE*NOUT] (last kh -> outp2); no
// bias (combine adds it). SPLITK==1: original behavior.
template<int KSTEPS, int SPLITK, int ASTRIDE, int NOUT, bool RELU,
         bool SCATTER, bool ADDBIAS, typename OutT>
__global__ __launch_bounds__(512, 1) void moe_gemm256_kernel(
    const __bf16* __restrict__ Am, const __bf16* __restrict__ Bp,
    const float* __restrict__ bias, const int* __restrict__ cnt,
    const int* __restrict__ base, const int* __restrict__ sortmap,
    OutT* __restrict__ outp, OutT* __restrict__ outp2)
{
  const int e  = blockIdx.z;
  const int ce = cnt[e];
  const int rb = base[e];
  const int cep = base[e + 1] - rb;        // padded count (multiple of 256)
  const int m  = blockIdx.y % 40;
  const int kh = (SPLITK > 1) ? (blockIdx.y / 40) : 0;
  const int m0 = m << 8;
  if (m0 >= cep) return;
  const int np = blockIdx.x, n0 = np << 8;

  constexpr int KH = KSTEPS / SPLITK;
  const int kbase = kh * KH * 64;          // element offset of this K-chunk

  const int tid = threadIdx.x, lane = tid & 63, wv = tid >> 6;
  const int wm = wv >> 2, wn = wv & 3;     // wave tile: rows wm*128, cols wn*64
  const int rl = lane & 15, sl = lane >> 4;

  __shared__ alignas(16) __bf16 lds[65536];   // 2 buffers x 64KB

  // per-lane staging SOURCES: 4 A + 4 B chunks (16B) per K-tile
  const __bf16* asrc[4];
  const __bf16* bsrc[4];
#pragma unroll
  for (int i = 0; i < 4; ++i) {
    const int c = (wv * 4 + i) * 64 + lane;       // chunk id 0..2047
    const int r = c >> 3, p = c & 7;              // tile row 0..255, granule
    const int koff = (p ^ (r & 7)) * 8 + kbase;
    asrc[i] = Am + (size_t)(rb + m0 + r) * ASTRIDE + koff;
    bsrc[i] = Bp + ((size_t)(e * (NOUT / 128) + np * 2) * 128 + r) * ASTRIDE + koff;
  }

  auto stage = [&](int buf, int ks) {
    __bf16* Ad = lds + buf * 32768;               // wave-uniform dests
    __bf16* Bd = Ad + 16384;
#pragma unroll
    for (int i = 0; i < 4; ++i)
      glds16(asrc[i] + ks * 64, Ad + (wv * 4 + i) * 512);
#pragma unroll
    for (int i = 0; i < 4; ++i)
      glds16(bsrc[i] + ks * 64, Bd + (wv * 4 + i) * 512);
  };

  f32x4 acc[8][4] = {};

  stage(0, 0);
  for (int ks = 0; ks < KH; ++ks) {
    const int buf = ks & 1;
    WAITV(0);                    // this K-tile's stages (issued last iter) landed
    SBAR();                      // visible to all waves; prev buf fully read
    if (ks + 1 < KH) stage(buf ^ 1, ks + 1);

    const char* Ab = (const char*)lds + buf * 65536 + wm * 16384;
    const char* Bb = (const char*)lds + buf * 65536 + 32768 + (wn >> 1) * 16384;

#pragma unroll
    for (int kk = 0; kk < 2; ++kk) {
      bf16x8 af[8];
#pragma unroll
      for (int mf = 0; mf < 8; ++mf) {
        const int row = mf * 16 + rl;
        af[mf] = *(const bf16x8*)(Ab + row * 128 + (((kk * 4 + sl) ^ (row & 7)) << 4));
      }
#pragma unroll
      for (int nh = 0; nh < 2; ++nh) {
        bf16x8 bf2[2];
#pragma unroll
        for (int nf2 = 0; nf2 < 2; ++nf2) {
          const int row = (wn & 1) * 64 + nh * 32 + nf2 * 16 + rl;
          bf2[nf2] = *(const bf16x8*)(Bb + row * 128 + (((kk * 4 + sl) ^ (row & 7)) << 4));
        }
        __builtin_amdgcn_s_setprio(1);
#pragma unroll
        for (int mf = 0; mf < 8; ++mf)
#pragma unroll
          for (int nf2 = 0; nf2 < 2; ++nf2)
            acc[mf][nh * 2 + nf2] = __builtin_amdgcn_mfma_f32_16x16x32_bf16(
                af[mf], bf2[nf2], acc[mf][nh * 2 + nf2], 0, 0, 0);
        __builtin_amdgcn_s_setprio(0);
      }
    }
  }

  // epilogue
  float bb[4] = {0.f, 0.f, 0.f, 0.f};
  if constexpr (ADDBIAS) {
#pragma unroll
    for (int nf = 0; nf < 4; ++nf)
      bb[nf] = bias[(size_t)e * NOUT + n0 + wn * 64 + nf * 16 + rl];
  }

  OutT* obase = outp;
  if constexpr (SPLITK > 1)
    obase = (kh == SPLITK - 1) ? outp2
                               : outp + (size_t)kh * ((size_t)PSTRIDE * NOUT);

#pragma unroll
  for (int mf = 0; mf < 8; ++mf) {
#pragma unroll
    for (int j = 0; j < 4; ++j) {
      const int gm = m0 + wm * 128 + mf * 16 + sl * 4 + j;
      if constexpr (SCATTER) {
        if (gm < ce) {
          const int tok = sortmap[rb + gm];
          OutT* op = obase + (size_t)tok * NOUT + n0 + wn * 64;
#pragma unroll
          for (int nf = 0; nf < 4; ++nf)
            op[nf * 16 + rl] = (OutT)(acc[mf][nf][j] + bb[nf]);
        }
      } else {
        OutT* op = obase + (size_t)(rb + gm) * NOUT + n0 + wn * 64;
        const bool live = gm < ce;
#pragma unroll
        for (int nf = 0; nf < 4; ++nf) {
          float v = acc[mf][nf][j] + bb[nf];
          if constexpr (RELU) v = fmaxf(v, 0.f);
          op[nf * 16 + rl] = live ? (OutT)v : (OutT)0.f;
        }
      }
    }
  }
}

// ------------------------------------------- combine split-K partials
// out[sortmap[r]][n] = sum_kh partial_kh[r][n] + b2[e][n], live rows only.
__global__ __launch_bounds__(256) void combine_kernel(
    const __bf16* __restrict__ p0, const __bf16* __restrict__ p3,
    const float* __restrict__ b2, const int* __restrict__ cnt,
    const int* __restrict__ base, const int* __restrict__ sortmap,
    float* __restrict__ out)
{
  const int r = blockIdx.x;
  int e = 0;
#pragma unroll
  for (int ee = 0; ee < NEXP; ++ee) if (r >= base[ee + 1]) e = ee + 1;
  if (e >= NEXP || (r - base[e]) >= cnt[e]) return;   // pad / out of range
  const int tok = sortmap[r];
  const int n = threadIdx.x * 4;
  const size_t off = (size_t)r * DMODEL + n;
  const size_t stride = (size_t)PSTRIDE * DMODEL;
  float a0 = 0.f, a1 = 0.f, a2 = 0.f, a3 = 0.f;
#pragma unroll
  for (int kh = 0; kh < 4; ++kh) {
    const __bf16* p = (kh == 3) ? (p3 + off) : (p0 + kh * stride + off);
    const bf16x4 v = *(const bf16x4*)p;
    a0 += (float)v[0]; a1 += (float)v[1];
    a2 += (float)v[2]; a3 += (float)v[3];
  }
  const float4 bbv = *(const float4*)(b2 + (size_t)e * DMODEL + n);
  float4 o = {a0 + bbv.x, a1 + bbv.y, a2 + bbv.z, a3 + bbv.w};
  *(float4*)(out + (size_t)tok * DMODEL + n) = o;
}

// ------------------------------------------------------------------ launch
extern "C" void kernel_launch(void* const* d_in, const int* in_sizes, int n_in,
                              void* d_out, int out_size, void* d_ws, size_t ws_size,
                              hipStream_t stream)
{
  const float* x  = (const float*)d_in[0];
  const float* gw = (const float*)d_in[1];
  const float* gb = (const float*)d_in[2];
  const float* w1 = (const float*)d_in[3];
  const float* b1 = (const float*)d_in[4];
  const float* w2 = (const float*)d_in[5];
  const float* b2 = (const float*)d_in[6];
  float* out = (float*)d_out;

  char* ws = (char*)d_ws;
  int*    cnt     = (int*)ws;                               // 32 B
  int*    base    = (int*)(ws + 256);                       // 9 ints
  int*    meta    = (int*)(ws + 4096);                      // 32 KB
  float*  wgt     = (float*)(ws + 40960);                   // 32 KB
  int*    sortmap = (int*)(ws + 81920);                     // 41 KB
  __bf16* xbf     = (__bf16*)(ws + ((size_t)1   << 20));    // 21 MB (10240 rows)
  __bf16* hmat    = (__bf16*)(ws + ((size_t)22  << 20));    // 84 MB
  __bf16* w1p     = (__bf16*)(ws + ((size_t)106 << 20));    // 64 MB

  const bool conc = ws_size >= ((size_t)235 << 20);

  zero_cnt_kernel<<<1, 64, 0, stream>>>(cnt);

  if (conc) {
    __bf16* w2p = (__bf16*)(ws + ((size_t)170 << 20));      // 64 MB (ends 234)
    // partials: kh 0..2 in dead w1p region (60 MB), kh 3 in dead xbf region
    __bf16* part0 = w1p;
    __bf16* part3 = xbf;

    fusedA_kernel<<<6144, 256, 0, stream>>>(
        x, gw, gb, wgt, cnt, meta, w1, w1p, w2, w2p);
    prefix_kernel<<<1, 64, 0, stream>>>(cnt, base);
    pack_x_kernel<<<NTOK / 2, 256, 0, stream>>>(x, wgt, meta, base, xbf, sortmap);
    moe_gemm256_kernel<DMODEL / 64, 1, DMODEL, HDIM, true, false, true, __bf16>
        <<<dim3(HDIM / 256, 40, NEXP), 512, 0, stream>>>(
            xbf, w1p, b1, cnt, base, sortmap, hmat, hmat);
    // GEMM2 split-K=4 (no atomics): 4 bf16 partials into dead regions
    moe_gemm256_kernel<HDIM / 64, 4, HDIM, DMODEL, false, false, false, __bf16>
        <<<dim3(DMODEL / 256, 4 * 40, NEXP), 512, 0, stream>>>(
            hmat, w2p, b2, cnt, base, sortmap, part0, part3);
    combine_kernel<<<PSTRIDE, 256, 0, stream>>>(
        part0, part3, b2, cnt, base, sortmap, out);
  } else {
    // serial fallback: pack w2 into w1p's space after GEMM1; direct GEMM2
    fusedA2_kernel<<<4096, 256, 0, stream>>>(
        x, gw, gb, wgt, cnt, meta, w1, w1p);
    prefix_kernel<<<1, 64, 0, stream>>>(cnt, base);
    pack_x_kernel<<<NTOK / 2, 256, 0, stream>>>(x, wgt, meta, base, xbf, sortmap);
    moe_gemm256_kernel<DMODEL / 64, 1, DMODEL, HDIM, true, false, true, __bf16>
        <<<dim3(HDIM / 256, 40, NEXP), 512, 0, stream>>>(
            xbf, w1p, b1, cnt, base, sortmap, hmat, hmat);
    pack_w_kernel<DMODEL, HDIM><<<2048, 256, 0, stream>>>(w2, w1p);
    moe_gemm256_kernel<HDIM / 64, 1, HDIM, DMODEL, false, true, true, float>
        <<<dim3(DMODEL / 256, 40, NEXP), 512, 0, stream>>>(
            hmat, w1p, b2, cnt, base, sortmap, out, out);
  }
}

// Round 20
// 341.506 us; speedup vs baseline: 1.0583x; 1.0583x over previous
//
#include <hip/hip_runtime.h>
#include <hip/hip_bf16.h>
#include <stdint.h>

typedef __attribute__((ext_vector_type(8))) __bf16 bf16x8;
typedef __attribute__((ext_vector_type(4))) __bf16 bf16x4;
typedef __attribute__((ext_vector_type(4))) float  f32x4;

#define NTOK   8192
#define DMODEL 1024
#define HDIM   4096
#define NEXP   8

__device__ __forceinline__ void glds16(const void* g, void* l) {
  __builtin_amdgcn_global_load_lds(
      (const __attribute__((address_space(1))) uint32_t*)g,
      (__attribute__((address_space(3))) uint32_t*)l, 16, 0, 0);
}

#define WAITV(N) asm volatile("s_waitcnt vmcnt(" #N ")" ::: "memory")
#define SBAR()  do { __builtin_amdgcn_sched_barrier(0); \
                     __builtin_amdgcn_s_barrier();      \
                     __builtin_amdgcn_sched_barrier(0); } while (0)

// ------------------------------------------------------------------ utils
__global__ void zero_cnt_kernel(int* cnt) {
  if (threadIdx.x < NEXP) cnt[threadIdx.x] = 0;
}

// base[e+1] = base[e] + round256(cnt[e])   (256-row M-tiles)
__global__ void prefix_kernel(const int* __restrict__ cnt, int* __restrict__ base) {
  if (threadIdx.x == 0) {
    int b = 0;
    base[0] = 0;
    for (int e = 0; e < NEXP; ++e) {
      b += (cnt[e] + 255) & ~255;
      base[e + 1] = b;
    }
  }
}

// ------------------------------------------------------------------ bodies
__device__ void gate_body(int bid,
    const float* __restrict__ x, const float* __restrict__ gw,
    const float* __restrict__ gb, float* __restrict__ wgt,
    int* __restrict__ cnt, int* __restrict__ meta)
{
  const int lane = threadIdx.x & 63;
  const int wv   = threadIdx.x >> 6;
  const int t    = (bid << 2) + wv;
  const float* xp = x + (size_t)t * DMODEL;

  float acc[NEXP];
#pragma unroll
  for (int e = 0; e < NEXP; ++e) acc[e] = 0.f;

#pragma unroll
  for (int j = 0; j < 4; ++j) {
    const int d = j * 256 + lane * 4;
    const float4 xv = *(const float4*)(xp + d);
    const float xs[4] = {xv.x, xv.y, xv.z, xv.w};
#pragma unroll
    for (int dd = 0; dd < 4; ++dd) {
      const float4 g0 = *(const float4*)(gw + (size_t)(d + dd) * NEXP);
      const float4 g1 = *(const float4*)(gw + (size_t)(d + dd) * NEXP + 4);
      acc[0] = fmaf(xs[dd], g0.x, acc[0]);
      acc[1] = fmaf(xs[dd], g0.y, acc[1]);
      acc[2] = fmaf(xs[dd], g0.z, acc[2]);
      acc[3] = fmaf(xs[dd], g0.w, acc[3]);
      acc[4] = fmaf(xs[dd], g1.x, acc[4]);
      acc[5] = fmaf(xs[dd], g1.y, acc[5]);
      acc[6] = fmaf(xs[dd], g1.z, acc[6]);
      acc[7] = fmaf(xs[dd], g1.w, acc[7]);
    }
  }
#pragma unroll
  for (int e = 0; e < NEXP; ++e) {
#pragma unroll
    for (int off = 32; off > 0; off >>= 1)
      acc[e] += __shfl_xor(acc[e], off, 64);
  }
  if (lane == 0) {
    float l[NEXP];
#pragma unroll
    for (int e = 0; e < NEXP; ++e) l[e] = acc[e] + gb[e];
    int i1 = 0; float m1 = l[0];
#pragma unroll
    for (int e = 1; e < NEXP; ++e) if (l[e] > m1) { m1 = l[e]; i1 = e; }
    int i2 = -1; float m2 = -3.402823466e38f;
#pragma unroll
    for (int e = 0; e < NEXP; ++e) if (e != i1 && l[e] > m2) { m2 = l[e]; i2 = e; }
    const int es = i1 > i2 ? i1 : i2;   // reference: last expert in loop wins
    float s = 0.f;
#pragma unroll
    for (int e = 0; e < NEXP; ++e) s += expf(l[e] - m1);
    const float w = expf(l[es] - m1) / s;
    wgt[t] = w;
    const int pos = atomicAdd(&cnt[es], 1);
    meta[t] = (es << 13) | pos;
  }
}

// pack_w via LDS transpose, 128k x 128n tile (BK=128), split load/store:
// src [E][K][N] fp32 -> dst [E][N][K] bf16 (k-contig rows; GEMM layout).
// Per-thread: g = t&31 fixed, k = (t>>5) + 8i -> 16 loads issued first
// (full MLP), then cvt+LDS store. LDS: element (k,n) at
// k*128 + pg*4 + (n&3), pg = ((n>>2) + 2*(k>>3) + (k&1)) & 31.
// Phase-2 writes: per wave 4 rows x 256B contiguous.
// Decode NP-FASTEST then E then KT for HBM channel spread.
template<int N, int K>
__device__ void packw_body(int bid, const float* __restrict__ src,
                           __bf16* __restrict__ dst)
{
  const int NP = N / 128;
  const int np = bid % NP;
  const int e  = (bid / NP) % NEXP;
  const int kt = bid / (NP * NEXP);     // < K/128
  const int t = threadIdx.x;
  __shared__ __bf16 sh[16384];          // 128 k x 128 n (granule-4 rotated)

  const float* sp = src + (size_t)e * K * N + (size_t)(kt * 128) * N + np * 128;
  const int g  = t & 31;                // col granule (4 floats)
  const int kb = t >> 5;                // 0..7

  float4 vv[16];
#pragma unroll
  for (int i = 0; i < 16; ++i)
    vv[i] = *(const float4*)(sp + (size_t)(kb + 8 * i) * N + g * 4);

#pragma unroll
  for (int i = 0; i < 16; ++i) {
    const int k = kb + 8 * i;
    bf16x4 o;
    o[0] = (__bf16)vv[i].x; o[1] = (__bf16)vv[i].y;
    o[2] = (__bf16)vv[i].z; o[3] = (__bf16)vv[i].w;
    const int pg = (g + 2 * (k >> 3) + (k & 1)) & 31;
    *(bf16x4*)&sh[k * 128 + pg * 4] = o;
  }
  __syncthreads();

  __bf16* dbase = dst + ((size_t)e * N + np * 128) * K + kt * 128;
  const int ks8 = t & 15;
  const int nb  = t >> 4;               // 0..15
#pragma unroll
  for (int i = 0; i < 8; ++i) {
    const int n = nb + 16 * i;
    bf16x8 v;
#pragma unroll
    for (int j = 0; j < 8; ++j) {
      const int k = ks8 * 8 + j;
      const int pg = ((n >> 2) + 2 * (k >> 3) + (k & 1)) & 31;
      v[j] = sh[k * 128 + pg * 4 + (n & 3)];
    }
    *(bf16x8*)(dbase + (size_t)n * K + ks8 * 8) = v;
  }
}

// fused A, INTERLEAVED streams: bid%3 -> {gate, pack_w1, pack_w2};
// 2048 chunks each -> 6144 blocks. Latency-bound gate waves co-reside
// with BW-bound pack waves the whole dispatch.
__global__ __launch_bounds__(256) void fusedA_kernel(
    const float* __restrict__ x, const float* __restrict__ gw,
    const float* __restrict__ gb, float* __restrict__ wgt,
    int* __restrict__ cnt, int* __restrict__ meta,
    const float* __restrict__ w1, __bf16* __restrict__ w1p,
    const float* __restrict__ w2, __bf16* __restrict__ w2p)
{
  const int c = blockIdx.x / 3, sel = blockIdx.x % 3;
  if (sel == 0)      gate_body(c, x, gw, gb, wgt, cnt, meta);
  else if (sel == 1) packw_body<HDIM, DMODEL>(c, w1, w1p);   // 8*32*8 = 2048
  else               packw_body<DMODEL, HDIM>(c, w2, w2p);   // 32*8*8 = 2048
}

// fused A fallback (gate + w1 only): bid%2, 4096 blocks
__global__ __launch_bounds__(256) void fusedA2_kernel(
    const float* __restrict__ x, const float* __restrict__ gw,
    const float* __restrict__ gb, float* __restrict__ wgt,
    int* __restrict__ cnt, int* __restrict__ meta,
    const float* __restrict__ w1, __bf16* __restrict__ w1p)
{
  const int c = blockIdx.x / 2, sel = blockIdx.x % 2;
  if (sel == 0) gate_body(c, x, gw, gb, wgt, cnt, meta);
  else          packw_body<HDIM, DMODEL>(c, w1, w1p);
}

// standalone pack_w (serial fallback for w2): 2048 blocks
template<int N, int K>
__global__ __launch_bounds__(256) void pack_w_kernel(
    const float* __restrict__ src, __bf16* __restrict__ dst)
{
  packw_body<N, K>(blockIdx.x, src, dst);
}

// -------------------------------------------------- pack x (sorted order)
// Pad rows keep stale bytes (finite bf16, harmless): GEMM1 writes 0 to hmat
// pad rows; GEMM2 only scatters gm<ce rows.
__global__ __launch_bounds__(256) void pack_x_kernel(
    const float* __restrict__ x, const float* __restrict__ wgt,
    const int* __restrict__ meta, const int* __restrict__ base,
    __bf16* __restrict__ xbf, int* __restrict__ sortmap)
{
  const int t = blockIdx.x * 2 + (threadIdx.x >> 7);
  const int l = threadIdx.x & 127;
  const int m = meta[t];
  const int es = m >> 13, pos = m & 8191;
  const int dst = base[es] + pos;
  const float w = wgt[t];
  const float4 a = *(const float4*)(x + (size_t)t * DMODEL + l * 8);
  const float4 b = *(const float4*)(x + (size_t)t * DMODEL + l * 8 + 4);
  bf16x8 o;
  o[0] = (__bf16)(a.x * w); o[1] = (__bf16)(a.y * w);
  o[2] = (__bf16)(a.z * w); o[3] = (__bf16)(a.w * w);
  o[4] = (__bf16)(b.x * w); o[5] = (__bf16)(b.y * w);
  o[6] = (__bf16)(b.z * w); o[7] = (__bf16)(b.w * w);
  *(bf16x8*)(xbf + (size_t)dst * DMODEL + l * 8) = o;
  if (l == 0) sortmap[dst] = t;
}

// ------------------------------------------------------------------ GEMM
// r7's verified core: 256x256 tile, 8 waves (2M x 4N, wave tile 128x64),
// BK=64, 2-buffer LDS (128KB), per K-tile { WAITV(0); barrier; stage next
// tile into other buffer; compute }. LDS rows 128B, granule phys = q^(row&7),
// swizzle at glds SOURCE (wave-uniform linear dest, m104 rule). Grid (np,m,e).
template<int KSTEPS, int ASTRIDE, int NOUT, bool RELU, bool SCATTER, typename OutT>
__global__ __launch_bounds__(512, 1) void moe_gemm256_kernel(
    const __bf16* __restrict__ Am, const __bf16* __restrict__ Bp,
    const float* __restrict__ bias, const int* __restrict__ cnt,
    const int* __restrict__ base, const int* __restrict__ sortmap,
    OutT* __restrict__ outp)
{
  const int e  = blockIdx.z;
  const int ce = cnt[e];
  const int rb = base[e];
  const int cep = base[e + 1] - rb;        // padded count (multiple of 256)
  const int m0 = blockIdx.y << 8;
  if (m0 >= cep) return;
  const int np = blockIdx.x, n0 = np << 8;

  const int tid = threadIdx.x, lane = tid & 63, wv = tid >> 6;
  const int wm = wv >> 2, wn = wv & 3;     // wave tile: rows wm*128, cols wn*64
  const int rl = lane & 15, sl = lane >> 4;

  __shared__ alignas(16) __bf16 lds[65536];   // 2 buffers x 64KB

  // per-lane staging SOURCES: 4 A + 4 B chunks (16B) per K-tile
  const __bf16* asrc[4];
  const __bf16* bsrc[4];
#pragma unroll
  for (int i = 0; i < 4; ++i) {
    const int c = (wv * 4 + i) * 64 + lane;       // chunk id 0..2047
    const int r = c >> 3, p = c & 7;              // tile row 0..255, granule
    const int koff = (p ^ (r & 7)) * 8;
    asrc[i] = Am + (size_t)(rb + m0 + r) * ASTRIDE + koff;
    bsrc[i] = Bp + ((size_t)(e * (NOUT / 128) + np * 2) * 128 + r) * ASTRIDE + koff;
  }

  auto stage = [&](int buf, int ks) {
    __bf16* Ad = lds + buf * 32768;               // wave-uniform dests
    __bf16* Bd = Ad + 16384;
#pragma unroll
    for (int i = 0; i < 4; ++i)
      glds16(asrc[i] + ks * 64, Ad + (wv * 4 + i) * 512);
#pragma unroll
    for (int i = 0; i < 4; ++i)
      glds16(bsrc[i] + ks * 64, Bd + (wv * 4 + i) * 512);
  };

  f32x4 acc[8][4] = {};

  stage(0, 0);
  for (int ks = 0; ks < KSTEPS; ++ks) {
    const int buf = ks & 1;
    WAITV(0);                    // this K-tile's stages (issued last iter) landed
    SBAR();                      // visible to all waves; prev buf fully read
    if (ks + 1 < KSTEPS) stage(buf ^ 1, ks + 1);

    const char* Ab = (const char*)lds + buf * 65536 + wm * 16384;
    const char* Bb = (const char*)lds + buf * 65536 + 32768 + (wn >> 1) * 16384;

#pragma unroll
    for (int kk = 0; kk < 2; ++kk) {
      bf16x8 af[8];
#pragma unroll
      for (int mf = 0; mf < 8; ++mf) {
        const int row = mf * 16 + rl;
        af[mf] = *(const bf16x8*)(Ab + row * 128 + (((kk * 4 + sl) ^ (row & 7)) << 4));
      }
#pragma unroll
      for (int nh = 0; nh < 2; ++nh) {
        bf16x8 bf2[2];
#pragma unroll
        for (int nf2 = 0; nf2 < 2; ++nf2) {
          const int row = (wn & 1) * 64 + nh * 32 + nf2 * 16 + rl;
          bf2[nf2] = *(const bf16x8*)(Bb + row * 128 + (((kk * 4 + sl) ^ (row & 7)) << 4));
        }
        __builtin_amdgcn_s_setprio(1);
#pragma unroll
        for (int mf = 0; mf < 8; ++mf)
#pragma unroll
          for (int nf2 = 0; nf2 < 2; ++nf2)
            acc[mf][nh * 2 + nf2] = __builtin_amdgcn_mfma_f32_16x16x32_bf16(
                af[mf], bf2[nf2], acc[mf][nh * 2 + nf2], 0, 0, 0);
        __builtin_amdgcn_s_setprio(0);
      }
    }
  }

  // epilogue: bias (+relu); sorted write or token scatter
  float bb[4];
#pragma unroll
  for (int nf = 0; nf < 4; ++nf)
    bb[nf] = bias[(size_t)e * NOUT + n0 + wn * 64 + nf * 16 + rl];

#pragma unroll
  for (int mf = 0; mf < 8; ++mf) {
#pragma unroll
    for (int j = 0; j < 4; ++j) {
      const int gm = m0 + wm * 128 + mf * 16 + sl * 4 + j;
      if constexpr (SCATTER) {
        if (gm < ce) {
          const int tok = sortmap[rb + gm];
          OutT* op = outp + (size_t)tok * NOUT + n0 + wn * 64;
#pragma unroll
          for (int nf = 0; nf < 4; ++nf)
            op[nf * 16 + rl] = (OutT)(acc[mf][nf][j] + bb[nf]);
        }
      } else {
        OutT* op = outp + (size_t)(rb + gm) * NOUT + n0 + wn * 64;
        const bool live = gm < ce;
#pragma unroll
        for (int nf = 0; nf < 4; ++nf) {
          float v = acc[mf][nf][j] + bb[nf];
          if constexpr (RELU) v = fmaxf(v, 0.f);
          op[nf * 16 + rl] = live ? (OutT)v : (OutT)0.f;
        }
      }
    }
  }
}

// ------------------------------------------------------------------ launch
extern "C" void kernel_launch(void* const* d_in, const int* in_sizes, int n_in,
                              void* d_out, int out_size, void* d_ws, size_t ws_size,
                              hipStream_t stream)
{
  const float* x  = (const float*)d_in[0];
  const float* gw = (const float*)d_in[1];
  const float* gb = (const float*)d_in[2];
  const float* w1 = (const float*)d_in[3];
  const float* b1 = (const float*)d_in[4];
  const float* w2 = (const float*)d_in[5];
  const float* b2 = (const float*)d_in[6];
  float* out = (float*)d_out;

  char* ws = (char*)d_ws;
  int*    cnt     = (int*)ws;                               // 32 B
  int*    base    = (int*)(ws + 256);                       // 9 ints
  int*    meta    = (int*)(ws + 4096);                      // 32 KB
  float*  wgt     = (float*)(ws + 40960);                   // 32 KB
  int*    sortmap = (int*)(ws + 81920);                     // 41 KB
  __bf16* xbf     = (__bf16*)(ws + ((size_t)1   << 20));    // <= 21 MB (10232 rows)
  __bf16* hmat    = (__bf16*)(ws + ((size_t)22  << 20));    // <= 84 MB
  __bf16* w1p     = (__bf16*)(ws + ((size_t)106 << 20));    // 64 MB

  const bool conc = ws_size >= ((size_t)235 << 20);

  zero_cnt_kernel<<<1, 64, 0, stream>>>(cnt);

  if (conc) {
    __bf16* w2p = (__bf16*)(ws + ((size_t)170 << 20));      // 64 MB (ends 234)
    // gate + pack_w1 + pack_w2, interleaved at bid granularity
    fusedA_kernel<<<6144, 256, 0, stream>>>(
        x, gw, gb, wgt, cnt, meta, w1, w1p, w2, w2p);
    prefix_kernel<<<1, 64, 0, stream>>>(cnt, base);
    pack_x_kernel<<<NTOK / 2, 256, 0, stream>>>(x, wgt, meta, base, xbf, sortmap);
    moe_gemm256_kernel<DMODEL / 64, DMODEL, HDIM, true, false, __bf16>
        <<<dim3(HDIM / 256, 40, NEXP), 512, 0, stream>>>(
            xbf, w1p, b1, cnt, base, sortmap, hmat);
    moe_gemm256_kernel<HDIM / 64, HDIM, DMODEL, false, true, float>
        <<<dim3(DMODEL / 256, 40, NEXP), 512, 0, stream>>>(
            hmat, w2p, b2, cnt, base, sortmap, out);
  } else {
    // serial fallback: pack w2 into w1p's space after GEMM1
    fusedA2_kernel<<<4096, 256, 0, stream>>>(
        x, gw, gb, wgt, cnt, meta, w1, w1p);
    prefix_kernel<<<1, 64, 0, stream>>>(cnt, base);
    pack_x_kernel<<<NTOK / 2, 256, 0, stream>>>(x, wgt, meta, base, xbf, sortmap);
    moe_gemm256_kernel<DMODEL / 64, DMODEL, HDIM, true, false, __bf16>
        <<<dim3(HDIM / 256, 40, NEXP), 512, 0, stream>>>(
            xbf, w1p, b1, cnt, base, sortmap, hmat);
    pack_w_kernel<DMODEL, HDIM><<<2048, 256, 0, stream>>>(w2, w1p);
    moe_gemm256_kernel<HDIM / 64, HDIM, DMODEL, false, true, float>
        <<<dim3(DMODEL / 256, 40, NEXP), 512, 0, stream>>>(
            hmat, w1p, b2, cnt, base, sortmap, out);
  }
}